// Round 1
// baseline (570.570 us; speedup 1.0000x reference)
//
#include <hip/hip_runtime.h>
#include <hip/hip_bf16.h>
#include <math.h>

// ---------- helpers ----------
__device__ __forceinline__ float bflo(unsigned u) { union { unsigned x; float f; } c; c.x = u << 16; return c.f; }
__device__ __forceinline__ float bfhi(unsigned u) { union { unsigned x; float f; } c; c.x = u & 0xffff0000u; return c.f; }
__device__ __forceinline__ unsigned short f2bf(float f) {
    union { float f; unsigned u; } c; c.f = f;
    unsigned r = c.u + 0x7fffu + ((c.u >> 16) & 1u);
    return (unsigned short)(r >> 16);
}

typedef __bf16 bf16x8_t __attribute__((ext_vector_type(8)));
typedef float  f32x4_t  __attribute__((ext_vector_type(4)));

// ---------- fp32 -> bf16 weight conversion ----------
__global__ void cvt_f2bf(const float* __restrict__ in, unsigned short* __restrict__ out, int n) {
    int i = blockIdx.x * 256 + threadIdx.x;
    if (i < n) out[i] = f2bf(in[i]);
}

// ---------- LayerNorm (optionally fused with shift+window-partition gather) ----------
// GATHER=1: dest row r is in window order; source row is original token after roll(-4,-4).
template<int GATHER>
__global__ void ln_kernel(const float* __restrict__ x, const float* __restrict__ g,
                          const float* __restrict__ b, unsigned short* __restrict__ out) {
    int row  = blockIdx.x * 4 + (threadIdx.x >> 6);
    int lane = threadIdx.x & 63;
    int src;
    if (GATHER) {
        int bb = row >> 12;
        int rem = row & 4095;
        int winid = rem >> 6, tok = rem & 63;
        int wi = winid >> 3, wj = winid & 7;
        int ii = tok >> 3,  jj = tok & 7;
        int hh = (wi * 8 + ii + 4) & 63;     // roll(-4): shifted[h'] = x[(h'+4)%64]
        int ww = (wj * 8 + jj + 4) & 63;
        src = (bb << 12) + hh * 64 + ww;
    } else {
        src = row;
    }
    const float4 v = *(const float4*)(x + (size_t)src * 256 + lane * 4);
    float s  = v.x + v.y + v.z + v.w;
    float s2 = v.x*v.x + v.y*v.y + v.z*v.z + v.w*v.w;
    #pragma unroll
    for (int off = 32; off > 0; off >>= 1) {
        s  += __shfl_xor(s,  off, 64);
        s2 += __shfl_xor(s2, off, 64);
    }
    float mean = s * (1.0f / 256.0f);
    float var  = s2 * (1.0f / 256.0f) - mean * mean;
    float rstd = rsqrtf(var + 1e-5f);
    int c0 = lane * 4;
    float4 gg  = *(const float4*)(g + c0);
    float4 bb4 = *(const float4*)(b + c0);
    ushort4 o;
    o.x = f2bf((v.x - mean) * rstd * gg.x + bb4.x);
    o.y = f2bf((v.y - mean) * rstd * gg.y + bb4.y);
    o.z = f2bf((v.z - mean) * rstd * gg.z + bb4.z);
    o.w = f2bf((v.w - mean) * rstd * gg.w + bb4.w);
    *(ushort4*)(out + (size_t)row * 256 + c0) = o;
}

// ---------- generic MFMA GEMM: C[M,N] = A[M,K](bf16) * Bw[N,K]^T(bf16) + bias ----------
// block = 256 threads (4 waves), each wave a 32x32 tile, block covers 64x64.
// MODE 0: store bf16         MODE 1: gelu(exact) -> bf16
// MODE 2: window-reverse+unshift scatter, += shortcut, store fp32
// MODE 3: += addf (same row), store fp32
template<int MODE>
__global__ void gemm_bt(const unsigned short* __restrict__ A,
                        const unsigned short* __restrict__ Bw,
                        const float* __restrict__ bias,
                        int M, int N, int K,
                        unsigned short* __restrict__ obf,
                        float* __restrict__ of32,
                        const float* __restrict__ addf) {
    int lane = threadIdx.x & 63;
    int wave = threadIdx.x >> 6;
    int m0 = blockIdx.x * 64 + (wave >> 1) * 32;
    int n0 = blockIdx.y * 64 + (wave & 1) * 32;
    int lr = lane & 15;     // fragment row/col
    int kg = lane >> 4;     // k-group (0..3) -> k offset kg*8

    f32x4_t acc[2][2];
    #pragma unroll
    for (int i = 0; i < 2; ++i)
        #pragma unroll
        for (int j = 0; j < 2; ++j) { acc[i][j][0]=0.f; acc[i][j][1]=0.f; acc[i][j][2]=0.f; acc[i][j][3]=0.f; }

    const unsigned short* a0p = A  + (size_t)(m0 + lr) * K + kg * 8;
    const unsigned short* a1p = a0p + (size_t)16 * K;
    const unsigned short* b0p = Bw + (size_t)(n0 + lr) * K + kg * 8;
    const unsigned short* b1p = b0p + (size_t)16 * K;

    for (int k0 = 0; k0 < K; k0 += 32) {
        bf16x8_t a0 = *(const bf16x8_t*)(a0p + k0);
        bf16x8_t a1 = *(const bf16x8_t*)(a1p + k0);
        bf16x8_t b0 = *(const bf16x8_t*)(b0p + k0);
        bf16x8_t b1 = *(const bf16x8_t*)(b1p + k0);
        acc[0][0] = __builtin_amdgcn_mfma_f32_16x16x32_bf16(a0, b0, acc[0][0], 0, 0, 0);
        acc[0][1] = __builtin_amdgcn_mfma_f32_16x16x32_bf16(a0, b1, acc[0][1], 0, 0, 0);
        acc[1][0] = __builtin_amdgcn_mfma_f32_16x16x32_bf16(a1, b0, acc[1][0], 0, 0, 0);
        acc[1][1] = __builtin_amdgcn_mfma_f32_16x16x32_bf16(a1, b1, acc[1][1], 0, 0, 0);
    }

    #pragma unroll
    for (int rb = 0; rb < 2; ++rb) {
        #pragma unroll
        for (int cb = 0; cb < 2; ++cb) {
            int col = n0 + cb * 16 + lr;
            float bv = bias[col];
            #pragma unroll
            for (int i = 0; i < 4; ++i) {
                int row = m0 + rb * 16 + kg * 4 + i;
                float v = acc[rb][cb][i] + bv;
                if (MODE == 0) {
                    obf[(size_t)row * N + col] = f2bf(v);
                } else if (MODE == 1) {
                    float gv = 0.5f * v * (1.0f + erff(v * 0.70710678118654752f));
                    obf[(size_t)row * N + col] = f2bf(gv);
                } else if (MODE == 2) {
                    int bb = row >> 12;
                    int rem = row & 4095;
                    int winid = rem >> 6, tok = rem & 63;
                    int wi = winid >> 3, wj = winid & 7;
                    int ii = tok >> 3,  jj = tok & 7;
                    int hh = (wi * 8 + ii + 4) & 63;   // roll(+4): dest[(h2+4)%64]
                    int ww = (wj * 8 + jj + 4) & 63;
                    size_t dst = ((size_t)(bb << 12) + hh * 64 + ww) * 256 + col;
                    of32[dst] = addf[dst] + v;
                } else {
                    size_t dst = (size_t)row * N + col;
                    of32[dst] = addf[dst] + v;
                }
            }
        }
    }
}

// ---------- attention: one block (64 threads) per (window-batch, head) ----------
__global__ void __launch_bounds__(64) attn_kernel(
        const unsigned short* __restrict__ q,
        const unsigned short* __restrict__ k,
        const unsigned short* __restrict__ v,
        const float* __restrict__ relt,
        unsigned short* __restrict__ ctx) {
    __shared__ float ks[64][32];
    __shared__ float vs[64][32];
    int wh = blockIdx.x;
    int wg = wh >> 3;        // global window 0..511
    int h  = wh & 7;         // head
    int win = wg & 63;       // window within image (for mask)
    int t = threadIdx.x;     // token row 0..63

    size_t rowbase = ((size_t)wg * 64 + t) * 256 + (size_t)h * 32;

    {   // stage K,V rows (bf16x8 vector loads), unpack to fp32 LDS
        const uint4* kp = (const uint4*)(k + rowbase);
        const uint4* vp = (const uint4*)(v + rowbase);
        #pragma unroll
        for (int qd = 0; qd < 4; ++qd) {
            uint4 ku = kp[qd], vu = vp[qd];
            unsigned ak[4] = {ku.x, ku.y, ku.z, ku.w};
            unsigned av[4] = {vu.x, vu.y, vu.z, vu.w};
            #pragma unroll
            for (int e = 0; e < 4; ++e) {
                ks[t][qd*8 + e*2 + 0] = bflo(ak[e]);
                ks[t][qd*8 + e*2 + 1] = bfhi(ak[e]);
                vs[t][qd*8 + e*2 + 0] = bflo(av[e]);
                vs[t][qd*8 + e*2 + 1] = bfhi(av[e]);
            }
        }
    }
    float qr[32];
    {
        const uint4* qp = (const uint4*)(q + rowbase);
        #pragma unroll
        for (int qd = 0; qd < 4; ++qd) {
            uint4 qu = qp[qd];
            unsigned aq[4] = {qu.x, qu.y, qu.z, qu.w};
            #pragma unroll
            for (int e = 0; e < 4; ++e) {
                qr[qd*8 + e*2 + 0] = bflo(aq[e]);
                qr[qd*8 + e*2 + 1] = bfhi(aq[e]);
            }
        }
    }
    __syncthreads();

    int ti = t >> 3, tj = t & 7;
    int wi = win >> 3, wj = win & 7;
    int hn = wi * 8 + ti, wn = wj * 8 + tj;
    int regn = (hn < 56 ? 0 : (hn < 60 ? 1 : 2)) * 3 + (wn < 56 ? 0 : (wn < 60 ? 1 : 2));

    float sc[64];
    float mx = -1e30f;
    #pragma unroll
    for (int m = 0; m < 64; ++m) {
        const float4* kr = (const float4*)(&ks[m][0]);
        float s = 0.f;
        #pragma unroll
        for (int qd = 0; qd < 8; ++qd) {
            float4 kv = kr[qd];
            s += qr[qd*4+0]*kv.x + qr[qd*4+1]*kv.y + qr[qd*4+2]*kv.z + qr[qd*4+3]*kv.w;
        }
        s *= 0.17677669529663687f;   // 1/sqrt(32)
        int mi = m >> 3, mj = m & 7;
        s += relt[((ti - mi + 7) * 15 + (tj - mj + 7)) * 8 + h];
        int hm = wi * 8 + mi, wm = wj * 8 + mj;
        int regm = (hm < 56 ? 0 : (hm < 60 ? 1 : 2)) * 3 + (wm < 56 ? 0 : (wm < 60 ? 1 : 2));
        if (regm != regn) s -= 100.f;
        sc[m] = s;
        mx = fmaxf(mx, s);
    }
    float sum = 0.f;
    #pragma unroll
    for (int m = 0; m < 64; ++m) { float e = expf(sc[m] - mx); sc[m] = e; sum += e; }
    float inv = 1.0f / sum;

    float o[32];
    #pragma unroll
    for (int d = 0; d < 32; ++d) o[d] = 0.f;
    #pragma unroll
    for (int m = 0; m < 64; ++m) {
        float p = sc[m];
        const float4* vr = (const float4*)(&vs[m][0]);
        #pragma unroll
        for (int qd = 0; qd < 8; ++qd) {
            float4 vv = vr[qd];
            o[qd*4+0] += p*vv.x; o[qd*4+1] += p*vv.y; o[qd*4+2] += p*vv.z; o[qd*4+3] += p*vv.w;
        }
    }
    unsigned short* cp = ctx + rowbase;
    #pragma unroll
    for (int d = 0; d < 32; ++d) cp[d] = f2bf(o[d] * inv);
}

// ---------- launch ----------
extern "C" void kernel_launch(void* const* d_in, const int* in_sizes, int n_in,
                              void* d_out, int out_size, void* d_ws, size_t ws_size,
                              hipStream_t stream) {
    const float* hs   = (const float*)d_in[0];
    const float* ln1g = (const float*)d_in[1];
    const float* ln1b = (const float*)d_in[2];
    const float* wq   = (const float*)d_in[3];
    const float* bq   = (const float*)d_in[4];
    const float* wk   = (const float*)d_in[5];
    const float* bk   = (const float*)d_in[6];
    const float* wv   = (const float*)d_in[7];
    const float* bv   = (const float*)d_in[8];
    const float* relt = (const float*)d_in[9];
    const float* wo   = (const float*)d_in[10];
    const float* bo   = (const float*)d_in[11];
    const float* ln2g = (const float*)d_in[12];
    const float* ln2b = (const float*)d_in[13];
    const float* w1   = (const float*)d_in[14];
    const float* b1   = (const float*)d_in[15];
    const float* w2   = (const float*)d_in[16];
    const float* b2   = (const float*)d_in[17];
    float* out = (float*)d_out;

    const size_t NTOK = 32768;                 // B * H * W
    size_t off = 0;
    auto carve = [&](size_t bytes) { void* p = (char*)d_ws + off; off += (bytes + 255) & ~(size_t)255; return p; };
    unsigned short* wq_b = (unsigned short*)carve(65536ull * 2);
    unsigned short* wk_b = (unsigned short*)carve(65536ull * 2);
    unsigned short* wv_b = (unsigned short*)carve(65536ull * 2);
    unsigned short* wo_b = (unsigned short*)carve(65536ull * 2);
    unsigned short* w1_b = (unsigned short*)carve(262144ull * 2);
    unsigned short* w2_b = (unsigned short*)carve(262144ull * 2);
    float*          hidden = (float*)carve(NTOK * 256 * 4);
    unsigned short* xw = (unsigned short*)carve(NTOK * 256 * 2);   // also reused as y (LN2 out)
    unsigned short* qb = (unsigned short*)carve(NTOK * 256 * 2);   // q; h1 overlays q..ctx (64MB)
    unsigned short* kb = (unsigned short*)carve(NTOK * 256 * 2);
    unsigned short* vb = (unsigned short*)carve(NTOK * 256 * 2);
    unsigned short* cx = (unsigned short*)carve(NTOK * 256 * 2);
    unsigned short* h1 = qb;   // [32768,1024] bf16 = 64MB, reuses q/k/v/ctx region
    unsigned short* yb = xw;

    // 1) weights -> bf16
    cvt_f2bf<<<256,  256, 0, stream>>>(wq, wq_b, 65536);
    cvt_f2bf<<<256,  256, 0, stream>>>(wk, wk_b, 65536);
    cvt_f2bf<<<256,  256, 0, stream>>>(wv, wv_b, 65536);
    cvt_f2bf<<<256,  256, 0, stream>>>(wo, wo_b, 65536);
    cvt_f2bf<<<1024, 256, 0, stream>>>(w1, w1_b, 262144);
    cvt_f2bf<<<1024, 256, 0, stream>>>(w2, w2_b, 262144);

    // 2) LN1 fused with cyclic shift + window partition -> xw (window-ordered, bf16)
    ln_kernel<1><<<8192, 256, 0, stream>>>(hs, ln1g, ln1b, xw);

    // 3) QKV projections
    dim3 g256(512, 4);
    gemm_bt<0><<<g256, 256, 0, stream>>>(xw, wq_b, bq, 32768, 256, 256, qb, nullptr, nullptr);
    gemm_bt<0><<<g256, 256, 0, stream>>>(xw, wk_b, bk, 32768, 256, 256, kb, nullptr, nullptr);
    gemm_bt<0><<<g256, 256, 0, stream>>>(xw, wv_b, bv, 32768, 256, 256, vb, nullptr, nullptr);

    // 4) windowed attention with rel-pos bias + shift mask
    attn_kernel<<<4096, 64, 0, stream>>>(qb, kb, vb, relt, cx);

    // 5) output projection + window reverse + reverse shift + residual -> hidden (fp32)
    gemm_bt<2><<<g256, 256, 0, stream>>>(cx, wo_b, bo, 32768, 256, 256, nullptr, hidden, hs);

    // 6) LN2 -> y (bf16)
    ln_kernel<0><<<8192, 256, 0, stream>>>(hidden, ln2g, ln2b, yb);

    // 7) MLP up + exact GELU -> h1 (bf16)
    dim3 g1024(512, 16);
    gemm_bt<1><<<g1024, 256, 0, stream>>>(yb, w1_b, b1, 32768, 1024, 256, h1, nullptr, nullptr);

    // 8) MLP down + residual -> out (fp32)
    gemm_bt<3><<<g256, 256, 0, stream>>>(h1, w2_b, b2, 32768, 256, 1024, nullptr, out, hidden);
}

// Round 2
// 329.152 us; speedup vs baseline: 1.7335x; 1.7335x over previous
//
#include <hip/hip_runtime.h>
#include <hip/hip_bf16.h>
#include <math.h>

// ---------- helpers ----------
__device__ __forceinline__ float bflo(unsigned u) { union { unsigned x; float f; } c; c.x = u << 16; return c.f; }
__device__ __forceinline__ float bfhi(unsigned u) { union { unsigned x; float f; } c; c.x = u & 0xffff0000u; return c.f; }
__device__ __forceinline__ unsigned short f2bf(float f) {
    union { float f; unsigned u; } c; c.f = f;
    unsigned r = c.u + 0x7fffu + ((c.u >> 16) & 1u);
    return (unsigned short)(r >> 16);
}

typedef __bf16 bf16x8_t __attribute__((ext_vector_type(8)));
typedef float  f32x4_t  __attribute__((ext_vector_type(4)));

#define AS1 __attribute__((address_space(1)))
#define AS3 __attribute__((address_space(3)))
__device__ __forceinline__ void g2lds16(const void* g, void* l) {
    __builtin_amdgcn_global_load_lds((const AS1 unsigned int*)g, (AS3 unsigned int*)l, 16, 0, 0);
}

// ---------- fp32 -> bf16 weight conversion ----------
__global__ void cvt_f2bf(const float* __restrict__ in, unsigned short* __restrict__ out, int n) {
    int i = blockIdx.x * 256 + threadIdx.x;
    if (i < n) out[i] = f2bf(in[i]);
}

// ---------- LayerNorm (optionally fused with shift+window-partition gather) ----------
template<int GATHER>
__global__ void ln_kernel(const float* __restrict__ x, const float* __restrict__ g,
                          const float* __restrict__ b, unsigned short* __restrict__ out) {
    int row  = blockIdx.x * 4 + (threadIdx.x >> 6);
    int lane = threadIdx.x & 63;
    int src;
    if (GATHER) {
        int bb = row >> 12;
        int rem = row & 4095;
        int winid = rem >> 6, tok = rem & 63;
        int wi = winid >> 3, wj = winid & 7;
        int ii = tok >> 3,  jj = tok & 7;
        int hh = (wi * 8 + ii + 4) & 63;     // roll(-4)
        int ww = (wj * 8 + jj + 4) & 63;
        src = (bb << 12) + hh * 64 + ww;
    } else {
        src = row;
    }
    const float4 v = *(const float4*)(x + (size_t)src * 256 + lane * 4);
    float s  = v.x + v.y + v.z + v.w;
    float s2 = v.x*v.x + v.y*v.y + v.z*v.z + v.w*v.w;
    #pragma unroll
    for (int off = 32; off > 0; off >>= 1) {
        s  += __shfl_xor(s,  off, 64);
        s2 += __shfl_xor(s2, off, 64);
    }
    float mean = s * (1.0f / 256.0f);
    float var  = s2 * (1.0f / 256.0f) - mean * mean;
    float rstd = rsqrtf(var + 1e-5f);
    int c0 = lane * 4;
    float4 gg  = *(const float4*)(g + c0);
    float4 bb4 = *(const float4*)(b + c0);
    ushort4 o;
    o.x = f2bf((v.x - mean) * rstd * gg.x + bb4.x);
    o.y = f2bf((v.y - mean) * rstd * gg.y + bb4.y);
    o.z = f2bf((v.z - mean) * rstd * gg.z + bb4.z);
    o.w = f2bf((v.w - mean) * rstd * gg.w + bb4.w);
    *(ushort4*)(out + (size_t)row * 256 + c0) = o;
}

// ---------- m97-style tiled MFMA GEMM: C[M,N] = A[M,K] * Bw[N,K]^T + bias ----------
// 128x128 block tile, 4 waves in 2x2, each wave 64x64 = 4x4 MFMA 16x16x32.
// LDS staging via global_load_lds width 16 (wave-uniform base + lane*16, unpadded).
// MODE 0: bf16 out  MODE 1: gelu->bf16  MODE 2: window-reverse scatter +res fp32  MODE 3: +res fp32
template<int MODE>
__global__ __launch_bounds__(256) void gemm_tile(
        const unsigned short* __restrict__ A,
        const unsigned short* __restrict__ Bw,
        const float* __restrict__ bias,
        int M, int N, int K,
        unsigned short* __restrict__ obf,
        float* __restrict__ of32,
        const float* __restrict__ addf) {
    __shared__ unsigned short As[128 * 32];
    __shared__ unsigned short Bs[128 * 32];
    int t = threadIdx.x;
    int lane = t & 63, wave = t >> 6;
    int m0 = blockIdx.x * 128, n0 = blockIdx.y * 128;
    int wm = (wave >> 1) * 64, wn = (wave & 1) * 64;
    int lr = lane & 15, kg = lane >> 4;

    f32x4_t acc[4][4];
    #pragma unroll
    for (int i = 0; i < 4; ++i)
        #pragma unroll
        for (int j = 0; j < 4; ++j) { acc[i][j][0]=0.f; acc[i][j][1]=0.f; acc[i][j][2]=0.f; acc[i][j][3]=0.f; }

    // staging: thread t covers rows t/4 and 64+t/4, k-chunk (t%4)*8 (16B)
    int srow = t >> 2, schunk = (t & 3) * 8;
    const unsigned short* ga0 = A  + (size_t)(m0 + srow)      * K + schunk;
    const unsigned short* ga1 = A  + (size_t)(m0 + 64 + srow) * K + schunk;
    const unsigned short* gb0 = Bw + (size_t)(n0 + srow)      * K + schunk;
    const unsigned short* gb1 = Bw + (size_t)(n0 + 64 + srow) * K + schunk;
    unsigned short* la0 = &As[t * 8];
    unsigned short* la1 = &As[2048 + t * 8];
    unsigned short* lb0 = &Bs[t * 8];
    unsigned short* lb1 = &Bs[2048 + t * 8];

    for (int k0 = 0; k0 < K; k0 += 32) {
        __syncthreads();
        g2lds16(ga0 + k0, la0);
        g2lds16(ga1 + k0, la1);
        g2lds16(gb0 + k0, lb0);
        g2lds16(gb1 + k0, lb1);
        __syncthreads();
        bf16x8_t af[4], bfr[4];
        #pragma unroll
        for (int i = 0; i < 4; ++i)
            af[i] = *(const bf16x8_t*)&As[(wm + i * 16 + lr) * 32 + kg * 8];
        #pragma unroll
        for (int j = 0; j < 4; ++j)
            bfr[j] = *(const bf16x8_t*)&Bs[(wn + j * 16 + lr) * 32 + kg * 8];
        #pragma unroll
        for (int i = 0; i < 4; ++i)
            #pragma unroll
            for (int j = 0; j < 4; ++j)
                acc[i][j] = __builtin_amdgcn_mfma_f32_16x16x32_bf16(af[i], bfr[j], acc[i][j], 0, 0, 0);
    }

    #pragma unroll
    for (int i = 0; i < 4; ++i) {
        #pragma unroll
        for (int j = 0; j < 4; ++j) {
            int col = n0 + wn + j * 16 + lr;
            float bv = bias[col];
            #pragma unroll
            for (int e = 0; e < 4; ++e) {
                int row = m0 + wm + i * 16 + kg * 4 + e;
                float v = acc[i][j][e] + bv;
                if (MODE == 0) {
                    obf[(size_t)row * N + col] = f2bf(v);
                } else if (MODE == 1) {
                    float gv = 0.5f * v * (1.0f + erff(v * 0.70710678118654752f));
                    obf[(size_t)row * N + col] = f2bf(gv);
                } else if (MODE == 2) {
                    int bb = row >> 12;
                    int rem = row & 4095;
                    int winid = rem >> 6, tok = rem & 63;
                    int wi = winid >> 3, wj = winid & 7;
                    int ii = tok >> 3,  jj = tok & 7;
                    int hh = (wi * 8 + ii + 4) & 63;   // roll(+4)
                    int ww = (wj * 8 + jj + 4) & 63;
                    size_t dst = ((size_t)(bb << 12) + hh * 64 + ww) * 256 + col;
                    of32[dst] = addf[dst] + v;
                } else {
                    size_t dst = (size_t)row * N + col;
                    of32[dst] = addf[dst] + v;
                }
            }
        }
    }
}

// ---------- attention: one block (64 threads) per (window-batch, head) ----------
// qkv: [32768, 768] bf16 (q|k|v per row); ctx: [32768, 256] bf16
__global__ void __launch_bounds__(64) attn_kernel(
        const unsigned short* __restrict__ qkv,
        const float* __restrict__ relt,
        unsigned short* __restrict__ ctx) {
    __shared__ float ks[64][32];
    __shared__ float vs[64][32];
    int wh = blockIdx.x;
    int wg = wh >> 3;
    int h  = wh & 7;
    int win = wg & 63;
    int t = threadIdx.x;

    size_t rowbase = ((size_t)wg * 64 + t) * 768 + (size_t)h * 32;

    {
        const uint4* kp = (const uint4*)(qkv + rowbase + 256);
        const uint4* vp = (const uint4*)(qkv + rowbase + 512);
        #pragma unroll
        for (int qd = 0; qd < 4; ++qd) {
            uint4 ku = kp[qd], vu = vp[qd];
            unsigned ak[4] = {ku.x, ku.y, ku.z, ku.w};
            unsigned av[4] = {vu.x, vu.y, vu.z, vu.w};
            #pragma unroll
            for (int e = 0; e < 4; ++e) {
                ks[t][qd*8 + e*2 + 0] = bflo(ak[e]);
                ks[t][qd*8 + e*2 + 1] = bfhi(ak[e]);
                vs[t][qd*8 + e*2 + 0] = bflo(av[e]);
                vs[t][qd*8 + e*2 + 1] = bfhi(av[e]);
            }
        }
    }
    float qr[32];
    {
        const uint4* qp = (const uint4*)(qkv + rowbase);
        #pragma unroll
        for (int qd = 0; qd < 4; ++qd) {
            uint4 qu = qp[qd];
            unsigned aq[4] = {qu.x, qu.y, qu.z, qu.w};
            #pragma unroll
            for (int e = 0; e < 4; ++e) {
                qr[qd*8 + e*2 + 0] = bflo(aq[e]);
                qr[qd*8 + e*2 + 1] = bfhi(aq[e]);
            }
        }
    }
    __syncthreads();

    int ti = t >> 3, tj = t & 7;
    int wi = win >> 3, wj = win & 7;
    int hn = wi * 8 + ti, wn = wj * 8 + tj;
    int regn = (hn < 56 ? 0 : (hn < 60 ? 1 : 2)) * 3 + (wn < 56 ? 0 : (wn < 60 ? 1 : 2));

    float sc[64];
    float mx = -1e30f;
    #pragma unroll
    for (int m = 0; m < 64; ++m) {
        const float4* kr = (const float4*)(&ks[m][0]);
        float s = 0.f;
        #pragma unroll
        for (int qd = 0; qd < 8; ++qd) {
            float4 kv = kr[qd];
            s += qr[qd*4+0]*kv.x + qr[qd*4+1]*kv.y + qr[qd*4+2]*kv.z + qr[qd*4+3]*kv.w;
        }
        s *= 0.17677669529663687f;
        int mi = m >> 3, mj = m & 7;
        s += relt[((ti - mi + 7) * 15 + (tj - mj + 7)) * 8 + h];
        int hm = wi * 8 + mi, wm2 = wj * 8 + mj;
        int regm = (hm < 56 ? 0 : (hm < 60 ? 1 : 2)) * 3 + (wm2 < 56 ? 0 : (wm2 < 60 ? 1 : 2));
        if (regm != regn) s -= 100.f;
        sc[m] = s;
        mx = fmaxf(mx, s);
    }
    float sum = 0.f;
    #pragma unroll
    for (int m = 0; m < 64; ++m) { float e = expf(sc[m] - mx); sc[m] = e; sum += e; }
    float inv = 1.0f / sum;

    float o[32];
    #pragma unroll
    for (int d = 0; d < 32; ++d) o[d] = 0.f;
    #pragma unroll
    for (int m = 0; m < 64; ++m) {
        float p = sc[m];
        const float4* vr = (const float4*)(&vs[m][0]);
        #pragma unroll
        for (int qd = 0; qd < 8; ++qd) {
            float4 vv = vr[qd];
            o[qd*4+0] += p*vv.x; o[qd*4+1] += p*vv.y; o[qd*4+2] += p*vv.z; o[qd*4+3] += p*vv.w;
        }
    }
    unsigned short* cp = ctx + ((size_t)wg * 64 + t) * 256 + (size_t)h * 32;
    #pragma unroll
    for (int d = 0; d < 32; ++d) cp[d] = f2bf(o[d] * inv);
}

// ---------- launch ----------
extern "C" void kernel_launch(void* const* d_in, const int* in_sizes, int n_in,
                              void* d_out, int out_size, void* d_ws, size_t ws_size,
                              hipStream_t stream) {
    const float* hs   = (const float*)d_in[0];
    const float* ln1g = (const float*)d_in[1];
    const float* ln1b = (const float*)d_in[2];
    const float* wq   = (const float*)d_in[3];
    const float* bq   = (const float*)d_in[4];
    const float* wk   = (const float*)d_in[5];
    const float* bk   = (const float*)d_in[6];
    const float* wv   = (const float*)d_in[7];
    const float* bv   = (const float*)d_in[8];
    const float* relt = (const float*)d_in[9];
    const float* wo   = (const float*)d_in[10];
    const float* bo   = (const float*)d_in[11];
    const float* ln2g = (const float*)d_in[12];
    const float* ln2b = (const float*)d_in[13];
    const float* w1   = (const float*)d_in[14];
    const float* b1   = (const float*)d_in[15];
    const float* w2   = (const float*)d_in[16];
    const float* b2   = (const float*)d_in[17];
    float* out = (float*)d_out;

    const size_t NTOK = 32768;
    size_t off = 0;
    auto carve = [&](size_t bytes) { void* p = (char*)d_ws + off; off += (bytes + 255) & ~(size_t)255; return p; };
    unsigned short* wqkv_b = (unsigned short*)carve(768ull * 256 * 2);
    unsigned short* wo_b   = (unsigned short*)carve(65536ull * 2);
    unsigned short* w1_b   = (unsigned short*)carve(262144ull * 2);
    unsigned short* w2_b   = (unsigned short*)carve(262144ull * 2);
    float*          bqkv   = (float*)carve(768ull * 4);
    float*          hidden = (float*)carve(NTOK * 256 * 4);
    unsigned short* xw     = (unsigned short*)carve(NTOK * 256 * 2);  // also LN2 out
    unsigned short* qkvb   = (unsigned short*)carve(NTOK * 768 * 2);  // q|k|v
    unsigned short* cx     = (unsigned short*)carve(NTOK * 256 * 2);
    unsigned short* h1 = qkvb;   // [32768,1024] bf16 = 64MB overlays qkv+cx (67MB)
    unsigned short* yb = xw;

    // 1) weights -> bf16 (QKV packed into [768,256]); biases packed [768]
    cvt_f2bf<<<256,  256, 0, stream>>>(wq, wqkv_b,          65536);
    cvt_f2bf<<<256,  256, 0, stream>>>(wk, wqkv_b + 65536,  65536);
    cvt_f2bf<<<256,  256, 0, stream>>>(wv, wqkv_b + 131072, 65536);
    cvt_f2bf<<<256,  256, 0, stream>>>(wo, wo_b, 65536);
    cvt_f2bf<<<1024, 256, 0, stream>>>(w1, w1_b, 262144);
    cvt_f2bf<<<1024, 256, 0, stream>>>(w2, w2_b, 262144);
    hipMemcpyAsync(bqkv,       bq, 256 * 4, hipMemcpyDeviceToDevice, stream);
    hipMemcpyAsync(bqkv + 256, bk, 256 * 4, hipMemcpyDeviceToDevice, stream);
    hipMemcpyAsync(bqkv + 512, bv, 256 * 4, hipMemcpyDeviceToDevice, stream);

    // 2) LN1 + cyclic shift + window partition -> xw (bf16)
    ln_kernel<1><<<8192, 256, 0, stream>>>(hs, ln1g, ln1b, xw);

    // 3) fused QKV projection: [32768,256] x [768,256]^T
    gemm_tile<0><<<dim3(256, 6), 256, 0, stream>>>(xw, wqkv_b, bqkv, 32768, 768, 256, qkvb, nullptr, nullptr);

    // 4) windowed attention
    attn_kernel<<<4096, 64, 0, stream>>>(qkvb, relt, cx);

    // 5) out projection + window reverse + unshift + residual -> hidden (fp32)
    gemm_tile<2><<<dim3(256, 2), 256, 0, stream>>>(cx, wo_b, bo, 32768, 256, 256, nullptr, hidden, hs);

    // 6) LN2 -> yb (bf16)
    ln_kernel<0><<<8192, 256, 0, stream>>>(hidden, ln2g, ln2b, yb);

    // 7) MLP up + GELU -> h1 (bf16)
    gemm_tile<1><<<dim3(256, 8), 256, 0, stream>>>(yb, w1_b, b1, 32768, 1024, 256, h1, nullptr, nullptr);

    // 8) MLP down + residual -> out (fp32)
    gemm_tile<3><<<dim3(256, 2), 256, 0, stream>>>(h1, w2_b, b2, 32768, 256, 1024, nullptr, out, hidden);
}

// Round 3
// 274.269 us; speedup vs baseline: 2.0803x; 1.2001x over previous
//
#include <hip/hip_runtime.h>
#include <hip/hip_bf16.h>
#include <math.h>

// ---------- helpers ----------
__device__ __forceinline__ unsigned short f2bf(float f) {
    union { float f; unsigned u; } c; c.f = f;
    unsigned r = c.u + 0x7fffu + ((c.u >> 16) & 1u);
    return (unsigned short)(r >> 16);
}

typedef __bf16 bf16x8_t __attribute__((ext_vector_type(8)));
typedef float  f32x4_t  __attribute__((ext_vector_type(4)));

#define AS1 __attribute__((address_space(1)))
#define AS3 __attribute__((address_space(3)))
__device__ __forceinline__ void g2lds16(const void* g, void* l) {
    __builtin_amdgcn_global_load_lds((const AS1 unsigned int*)g, (AS3 unsigned int*)l, 16, 0, 0);
}

// ---------- all weights fp32 -> bf16 in one launch ----------
__global__ void cvt_all(const float* __restrict__ wq, const float* __restrict__ wk,
                        const float* __restrict__ wv, const float* __restrict__ wo,
                        const float* __restrict__ w1, const float* __restrict__ w2,
                        unsigned short* __restrict__ wqkv_b, unsigned short* __restrict__ wo_b,
                        unsigned short* __restrict__ w1_b, unsigned short* __restrict__ w2_b) {
    int i = blockIdx.x * 256 + threadIdx.x;   // index in float4 units
    const float* src; unsigned short* dst; int base;
    if (i < 16384)       { src = wq; dst = wqkv_b;          base = 0; }
    else if (i < 32768)  { src = wk; dst = wqkv_b + 65536;  base = 16384; }
    else if (i < 49152)  { src = wv; dst = wqkv_b + 131072; base = 32768; }
    else if (i < 65536)  { src = wo; dst = wo_b;            base = 49152; }
    else if (i < 131072) { src = w1; dst = w1_b;            base = 65536; }
    else                 { src = w2; dst = w2_b;            base = 131072; }
    int j = (i - base) * 4;
    float4 v = *(const float4*)(src + j);
    ushort4 o = { f2bf(v.x), f2bf(v.y), f2bf(v.z), f2bf(v.w) };
    *(ushort4*)(dst + j) = o;
}

// ---------- LayerNorm (optionally fused with shift+window-partition gather) ----------
template<int GATHER>
__global__ void ln_kernel(const float* __restrict__ x, const float* __restrict__ g,
                          const float* __restrict__ b, unsigned short* __restrict__ out) {
    int row  = blockIdx.x * 4 + (threadIdx.x >> 6);
    int lane = threadIdx.x & 63;
    int src;
    if (GATHER) {
        int bb = row >> 12;
        int rem = row & 4095;
        int winid = rem >> 6, tok = rem & 63;
        int wi = winid >> 3, wj = winid & 7;
        int ii = tok >> 3,  jj = tok & 7;
        int hh = (wi * 8 + ii + 4) & 63;     // roll(-4)
        int ww = (wj * 8 + jj + 4) & 63;
        src = (bb << 12) + hh * 64 + ww;
    } else {
        src = row;
    }
    const float4 v = *(const float4*)(x + (size_t)src * 256 + lane * 4);
    float s  = v.x + v.y + v.z + v.w;
    float s2 = v.x*v.x + v.y*v.y + v.z*v.z + v.w*v.w;
    #pragma unroll
    for (int off = 32; off > 0; off >>= 1) {
        s  += __shfl_xor(s,  off, 64);
        s2 += __shfl_xor(s2, off, 64);
    }
    float mean = s * (1.0f / 256.0f);
    float var  = s2 * (1.0f / 256.0f) - mean * mean;
    float rstd = rsqrtf(var + 1e-5f);
    int c0 = lane * 4;
    float4 gg  = *(const float4*)(g + c0);
    float4 bb4 = *(const float4*)(b + c0);
    ushort4 o;
    o.x = f2bf((v.x - mean) * rstd * gg.x + bb4.x);
    o.y = f2bf((v.y - mean) * rstd * gg.y + bb4.y);
    o.z = f2bf((v.z - mean) * rstd * gg.z + bb4.z);
    o.w = f2bf((v.w - mean) * rstd * gg.w + bb4.w);
    *(ushort4*)(out + (size_t)row * 256 + c0) = o;
}

// ---------- m97-style tiled MFMA GEMM: C[M,N] = A[M,K] * Bw[N,K]^T + bias ----------
template<int MODE>
__global__ __launch_bounds__(256) void gemm_tile(
        const unsigned short* __restrict__ A,
        const unsigned short* __restrict__ Bw,
        const float* __restrict__ bias,
        int M, int N, int K,
        unsigned short* __restrict__ obf,
        float* __restrict__ of32,
        const float* __restrict__ addf) {
    __shared__ unsigned short As[128 * 32];
    __shared__ unsigned short Bs[128 * 32];
    int t = threadIdx.x;
    int lane = t & 63, wave = t >> 6;
    int m0 = blockIdx.x * 128, n0 = blockIdx.y * 128;
    int wm = (wave >> 1) * 64, wn = (wave & 1) * 64;
    int lr = lane & 15, kg = lane >> 4;

    f32x4_t acc[4][4];
    #pragma unroll
    for (int i = 0; i < 4; ++i)
        #pragma unroll
        for (int j = 0; j < 4; ++j) { acc[i][j][0]=0.f; acc[i][j][1]=0.f; acc[i][j][2]=0.f; acc[i][j][3]=0.f; }

    int srow = t >> 2, schunk = (t & 3) * 8;
    const unsigned short* ga0 = A  + (size_t)(m0 + srow)      * K + schunk;
    const unsigned short* ga1 = A  + (size_t)(m0 + 64 + srow) * K + schunk;
    const unsigned short* gb0 = Bw + (size_t)(n0 + srow)      * K + schunk;
    const unsigned short* gb1 = Bw + (size_t)(n0 + 64 + srow) * K + schunk;
    unsigned short* la0 = &As[t * 8];
    unsigned short* la1 = &As[2048 + t * 8];
    unsigned short* lb0 = &Bs[t * 8];
    unsigned short* lb1 = &Bs[2048 + t * 8];

    for (int k0 = 0; k0 < K; k0 += 32) {
        __syncthreads();
        g2lds16(ga0 + k0, la0);
        g2lds16(ga1 + k0, la1);
        g2lds16(gb0 + k0, lb0);
        g2lds16(gb1 + k0, lb1);
        __syncthreads();
        bf16x8_t af[4], bfr[4];
        #pragma unroll
        for (int i = 0; i < 4; ++i)
            af[i] = *(const bf16x8_t*)&As[(wm + i * 16 + lr) * 32 + kg * 8];
        #pragma unroll
        for (int j = 0; j < 4; ++j)
            bfr[j] = *(const bf16x8_t*)&Bs[(wn + j * 16 + lr) * 32 + kg * 8];
        #pragma unroll
        for (int i = 0; i < 4; ++i)
            #pragma unroll
            for (int j = 0; j < 4; ++j)
                acc[i][j] = __builtin_amdgcn_mfma_f32_16x16x32_bf16(af[i], bfr[j], acc[i][j], 0, 0, 0);
    }

    #pragma unroll
    for (int i = 0; i < 4; ++i) {
        #pragma unroll
        for (int j = 0; j < 4; ++j) {
            int col = n0 + wn + j * 16 + lr;
            float bv = bias[col];
            #pragma unroll
            for (int e = 0; e < 4; ++e) {
                int row = m0 + wm + i * 16 + kg * 4 + e;
                float v = acc[i][j][e] + bv;
                if (MODE == 0) {
                    obf[(size_t)row * N + col] = f2bf(v);
                } else if (MODE == 1) {
                    float gv = 0.5f * v * (1.0f + erff(v * 0.70710678118654752f));
                    obf[(size_t)row * N + col] = f2bf(gv);
                } else if (MODE == 2) {
                    int bb = row >> 12;
                    int rem = row & 4095;
                    int winid = rem >> 6, tok = rem & 63;
                    int wi = winid >> 3, wj = winid & 7;
                    int ii = tok >> 3,  jj = tok & 7;
                    int hh = (wi * 8 + ii + 4) & 63;   // roll(+4)
                    int ww = (wj * 8 + jj + 4) & 63;
                    size_t dst = ((size_t)(bb << 12) + hh * 64 + ww) * 256 + col;
                    of32[dst] = addf[dst] + v;
                } else {
                    size_t dst = (size_t)row * N + col;
                    of32[dst] = addf[dst] + v;
                }
            }
        }
    }
}

// ---------- MFMA attention: 4 waves/block, each wave one (window-batch, head) ----------
// qkv: [32768, 768] bf16 (q|k|v); ctx: [32768, 256] bf16
#define PR 72   // P LDS row stride (shorts): 144B = 4 banks/row -> 2-way (free)
#define VR 72   // V^T LDS row stride
__global__ void __launch_bounds__(256) attn_mfma(
        const unsigned short* __restrict__ qkv,
        const float* __restrict__ relt,
        unsigned short* __restrict__ ctx) {
    __shared__ float rs[1800];
    __shared__ unsigned short Pl[4][64 * PR];
    __shared__ unsigned short Vt[4][32 * VR];

    int t = threadIdx.x;
    int lane = t & 63, wave = t >> 6;
    for (int i = t; i < 1800; i += 256) rs[i] = relt[i];
    __syncthreads();

    int wh = blockIdx.x * 4 + wave;
    int wg = wh >> 3, h = wh & 7;
    int win = wg & 63;
    int ln = lane & 15, quad = lane >> 4;

    unsigned short* P = &Pl[wave][0];
    unsigned short* V = &Vt[wave][0];
    const unsigned short* base = qkv + (size_t)wg * 64 * 768 + h * 32;

    // --- stage V^T: lane reads V row 'lane' (32 d contiguous), scatters to Vt[d][lane]
    union BF8 { bf16x8_t v; unsigned short s[8]; };
    {
        const bf16x8_t* vp = (const bf16x8_t*)(base + (size_t)lane * 768 + 512);
        BF8 vv[4];
        #pragma unroll
        for (int c = 0; c < 4; ++c) vv[c].v = vp[c];
        #pragma unroll
        for (int c = 0; c < 4; ++c)
            #pragma unroll
            for (int e = 0; e < 8; ++e)
                V[(c * 8 + e) * VR + lane] = vv[c].s[e];
    }

    // --- S = Q K^T : direct global fragment loads, 16 MFMAs (D=32 = one K step)
    bf16x8_t qa[4], kb[4];
    #pragma unroll
    for (int i = 0; i < 4; ++i)
        qa[i] = *(const bf16x8_t*)(base + (size_t)(i * 16 + ln) * 768 + quad * 8);
    #pragma unroll
    for (int j = 0; j < 4; ++j)
        kb[j] = *(const bf16x8_t*)(base + (size_t)(j * 16 + ln) * 768 + 256 + quad * 8);

    f32x4_t acc[4][4];
    #pragma unroll
    for (int i = 0; i < 4; ++i)
        #pragma unroll
        for (int j = 0; j < 4; ++j) { acc[i][j][0]=0.f; acc[i][j][1]=0.f; acc[i][j][2]=0.f; acc[i][j][3]=0.f; }
    #pragma unroll
    for (int i = 0; i < 4; ++i)
        #pragma unroll
        for (int j = 0; j < 4; ++j)
            acc[i][j] = __builtin_amdgcn_mfma_f32_16x16x32_bf16(qa[i], kb[j], acc[i][j], 0, 0, 0);

    // --- bias + mask + softmax (no max-subtract: |scores| <= ~3, masked = -100 -> exp==0)
    const float scale = 0.17677669529663687f;
    int wi = win >> 3, wj = win & 7;
    int mjv = ln & 7;
    int regm[4], mi[4];
    #pragma unroll
    for (int j = 0; j < 4; ++j) {
        mi[j] = j * 2 + (ln >> 3);
        int hm = wi * 8 + mi[j], wm = wj * 8 + mjv;
        regm[j] = (hm < 56 ? 0 : (hm < 60 ? 1 : 2)) * 3 + (wm < 56 ? 0 : (wm < 60 ? 1 : 2));
    }
    float inv[4][4];
    #pragma unroll
    for (int i = 0; i < 4; ++i) {
        #pragma unroll
        for (int e = 0; e < 4; ++e) {
            int q = i * 16 + quad * 4 + e;
            int ti = q >> 3, tj = q & 7;
            int hn = wi * 8 + ti, wn = wj * 8 + tj;
            int regn = (hn < 56 ? 0 : (hn < 60 ? 1 : 2)) * 3 + (wn < 56 ? 0 : (wn < 60 ? 1 : 2));
            float sum = 0.f;
            #pragma unroll
            for (int j = 0; j < 4; ++j) {
                float bv = rs[((ti - mi[j] + 7) * 15 + (tj - mjv + 7)) * 8 + h];
                float s = acc[i][j][e] * scale + bv + (regm[j] != regn ? -100.f : 0.f);
                float p = __expf(s);
                sum += p;
                P[q * PR + j * 16 + ln] = f2bf(p);
            }
            #pragma unroll
            for (int off = 1; off < 16; off <<= 1) sum += __shfl_xor(sum, off, 64);
            inv[i][e] = 1.0f / sum;
        }
    }
    __syncthreads();   // LDS visibility for P / Vt round-trip

    // --- O = P V : P in A-layout via ds_read_b128, V^T rows in B-layout
    bf16x8_t vb[2][2];
    #pragma unroll
    for (int jd = 0; jd < 2; ++jd)
        #pragma unroll
        for (int kc = 0; kc < 2; ++kc)
            vb[jd][kc] = *(const bf16x8_t*)&V[(jd * 16 + ln) * VR + kc * 32 + quad * 8];
    f32x4_t occ[4][2];
    #pragma unroll
    for (int i = 0; i < 4; ++i)
        #pragma unroll
        for (int jd = 0; jd < 2; ++jd) { occ[i][jd][0]=0.f; occ[i][jd][1]=0.f; occ[i][jd][2]=0.f; occ[i][jd][3]=0.f; }
    #pragma unroll
    for (int i = 0; i < 4; ++i) {
        #pragma unroll
        for (int kc = 0; kc < 2; ++kc) {
            bf16x8_t pf = *(const bf16x8_t*)&P[(i * 16 + ln) * PR + kc * 32 + quad * 8];
            occ[i][0] = __builtin_amdgcn_mfma_f32_16x16x32_bf16(pf, vb[0][kc], occ[i][0], 0, 0, 0);
            occ[i][1] = __builtin_amdgcn_mfma_f32_16x16x32_bf16(pf, vb[1][kc], occ[i][1], 0, 0, 0);
        }
    }

    // --- store ctx (bf16), normalize by row sum
    unsigned short* cbase = ctx + (size_t)wg * 64 * 256 + h * 32;
    #pragma unroll
    for (int i = 0; i < 4; ++i)
        #pragma unroll
        for (int e = 0; e < 4; ++e) {
            int q = i * 16 + quad * 4 + e;
            #pragma unroll
            for (int jd = 0; jd < 2; ++jd)
                cbase[(size_t)q * 256 + jd * 16 + ln] = f2bf(occ[i][jd][e] * inv[i][e]);
        }
}

// ---------- launch ----------
extern "C" void kernel_launch(void* const* d_in, const int* in_sizes, int n_in,
                              void* d_out, int out_size, void* d_ws, size_t ws_size,
                              hipStream_t stream) {
    const float* hs   = (const float*)d_in[0];
    const float* ln1g = (const float*)d_in[1];
    const float* ln1b = (const float*)d_in[2];
    const float* wq   = (const float*)d_in[3];
    const float* bq   = (const float*)d_in[4];
    const float* wk   = (const float*)d_in[5];
    const float* bk   = (const float*)d_in[6];
    const float* wv   = (const float*)d_in[7];
    const float* bv   = (const float*)d_in[8];
    const float* relt = (const float*)d_in[9];
    const float* wo   = (const float*)d_in[10];
    const float* bo   = (const float*)d_in[11];
    const float* ln2g = (const float*)d_in[12];
    const float* ln2b = (const float*)d_in[13];
    const float* w1   = (const float*)d_in[14];
    const float* b1   = (const float*)d_in[15];
    const float* w2   = (const float*)d_in[16];
    const float* b2   = (const float*)d_in[17];
    float* out = (float*)d_out;

    const size_t NTOK = 32768;
    size_t off = 0;
    auto carve = [&](size_t bytes) { void* p = (char*)d_ws + off; off += (bytes + 255) & ~(size_t)255; return p; };
    unsigned short* wqkv_b = (unsigned short*)carve(768ull * 256 * 2);
    unsigned short* wo_b   = (unsigned short*)carve(65536ull * 2);
    unsigned short* w1_b   = (unsigned short*)carve(262144ull * 2);
    unsigned short* w2_b   = (unsigned short*)carve(262144ull * 2);
    float*          bqkv   = (float*)carve(768ull * 4);
    float*          hidden = (float*)carve(NTOK * 256 * 4);
    unsigned short* xw     = (unsigned short*)carve(NTOK * 256 * 2);  // also LN2 out
    unsigned short* qkvb   = (unsigned short*)carve(NTOK * 768 * 2);  // q|k|v
    unsigned short* cx     = (unsigned short*)carve(NTOK * 256 * 2);
    unsigned short* h1 = qkvb;   // MLP hidden overlays qkv+cx
    unsigned short* yb = xw;

    // 1) all weights -> bf16 in one launch; biases packed [768] fp32
    cvt_all<<<768, 256, 0, stream>>>(wq, wk, wv, wo, w1, w2, wqkv_b, wo_b, w1_b, w2_b);
    hipMemcpyAsync(bqkv,       bq, 256 * 4, hipMemcpyDeviceToDevice, stream);
    hipMemcpyAsync(bqkv + 256, bk, 256 * 4, hipMemcpyDeviceToDevice, stream);
    hipMemcpyAsync(bqkv + 512, bv, 256 * 4, hipMemcpyDeviceToDevice, stream);

    // 2) LN1 + cyclic shift + window partition -> xw (bf16)
    ln_kernel<1><<<8192, 256, 0, stream>>>(hs, ln1g, ln1b, xw);

    // 3) fused QKV projection: [32768,256] x [768,256]^T
    gemm_tile<0><<<dim3(256, 6), 256, 0, stream>>>(xw, wqkv_b, bqkv, 32768, 768, 256, qkvb, nullptr, nullptr);

    // 4) windowed MFMA attention
    attn_mfma<<<1024, 256, 0, stream>>>(qkvb, relt, cx);

    // 5) out projection + window reverse + unshift + residual -> hidden (fp32)
    gemm_tile<2><<<dim3(256, 2), 256, 0, stream>>>(cx, wo_b, bo, 32768, 256, 256, nullptr, hidden, hs);

    // 6) LN2 -> yb (bf16)
    ln_kernel<0><<<8192, 256, 0, stream>>>(hidden, ln2g, ln2b, yb);

    // 7) MLP up + GELU -> h1 (bf16)
    gemm_tile<1><<<dim3(256, 8), 256, 0, stream>>>(yb, w1_b, b1, 32768, 1024, 256, h1, nullptr, nullptr);

    // 8) MLP down + residual -> out (fp32)
    gemm_tile<3><<<dim3(256, 2), 256, 0, stream>>>(h1, w2_b, b2, 32768, 256, 1024, nullptr, out, hidden);
}